// Round 5
// baseline (40.634 us; speedup 1.0000x reference)
//
#include <hip/hip_runtime.h>
#include <math.h>

typedef float v2f __attribute__((ext_vector_type(2)));

constexpr int BATCH = 4096;
constexpr int DIM   = 2048;
constexpr int REPS  = 8;
constexpr float INV2PI = 0.15915494309189535f;  // 1/(2*pi)

constexpr int TPB   = 256;
constexpr int GRIDX = DIM / TPB;       // 8
constexpr int GRIDY = 128;             // 1024 blocks = 4096 waves, fully resident @4w/SIMD
constexpr int BPB   = BATCH / GRIDY;   // 32 rows per block
constexpr int NCH   = BPB / 4;         // 8 chunks of 4 rows = 2 float2 pairs

// LDS staging pitches (coprime with 32 banks)
constexpr int TH_PITCH = 19, PW_PITCH = 9;
constexpr int LDS_FLOATS = TPB * TH_PITCH;

// ---- packed-fp32 helpers (plain VOP3P forms only; no modifiers) ----
static __device__ __forceinline__ v2f pk_fma(v2f a, v2f b, v2f c) {
    v2f d; asm("v_pk_fma_f32 %0, %1, %2, %3" : "=v"(d) : "v"(a), "v"(b), "v"(c)); return d;
}
static __device__ __forceinline__ v2f pk_fma_cs(v2f a, v2f b, v2f c) {  // c uniform -> sgpr pair
    v2f d; asm("v_pk_fma_f32 %0, %1, %2, %3" : "=v"(d) : "v"(a), "v"(b), "s"(c)); return d;
}
static __device__ __forceinline__ v2f pk_fma_bs(v2f a, v2f b, v2f c) {  // b uniform -> sgpr pair
    v2f d; asm("v_pk_fma_f32 %0, %1, %2, %3" : "=v"(d) : "v"(a), "s"(b), "v"(c)); return d;
}
static __device__ __forceinline__ v2f pk_mul(v2f a, v2f b) {
    v2f d; asm("v_pk_mul_f32 %0, %1, %2" : "=v"(d) : "v"(a), "v"(b)); return d;
}
static __device__ __forceinline__ v2f pk_mul_bs(v2f a, v2f b) {         // b uniform -> sgpr pair
    v2f d; asm("v_pk_mul_f32 %0, %1, %2" : "=v"(d) : "v"(a), "s"(b)); return d;
}

__global__ __launch_bounds__(TPB, 4)
void daruan_kernel(const float* __restrict__ x,       // (BATCH, DIM)
                   const float* __restrict__ theta,   // (DIM, 9, 2)
                   const float* __restrict__ paw,     // (DIM, 8)
                   const float* __restrict__ pab,     // (DIM, 8)
                   const float* __restrict__ postw,   // (DIM)
                   const float* __restrict__ postb,   // (DIM)
                   float* __restrict__ out)           // (BATCH, DIM)
{
    __shared__ float lds[LDS_FLOATS];
    const int t = threadIdx.x;
    const int d = blockIdx.x * TPB + t;

    // ---- phase 1: coalesced stage of theta ----
    {
        const float* gth = theta + (size_t)blockIdx.x * TPB * 18;
#pragma unroll
        for (int p = 0; p < 18; ++p) {
            const int idx = p * TPB + t;
            lds[(idx / 18) * TH_PITCH + (idx % 18)] = gth[idx];
        }
    }
    __syncthreads();

    // Trainable-RZ folding (verified R1-R4): RZ(t0[0]) + RY(t1[0]) -> initial
    // Bloch state; RZ(t0[r+1]) absorbed into rep r's encoding bias.
    v2f cy2[REPS], sy2[REPS], nsy2[REPS];
    float th0n[REPS], wr_[REPS], br_[REPS];
    v2f Xi2, Yi2, Zi2;
    {
        const float* th_l = lds + t * TH_PITCH;
        const float t00 = th_l[0] * INV2PI;
        const float X0  = __builtin_amdgcn_cosf(t00);
        const float Y0  = __builtin_amdgcn_sinf(t00);
        const float t10 = th_l[1] * INV2PI;
        const float c10 = __builtin_amdgcn_cosf(t10);
        const float s10 = __builtin_amdgcn_sinf(t10);
        Xi2 = v2f{X0 * c10, X0 * c10};
        Yi2 = v2f{Y0, Y0};
        Zi2 = v2f{-X0 * s10, -X0 * s10};
#pragma unroll
        for (int k = 0; k < REPS; ++k) {
            const float t1 = th_l[2 * k + 3] * INV2PI;   // theta1[k+1]
            const float c = __builtin_amdgcn_cosf(t1);
            const float s = __builtin_amdgcn_sinf(t1);
            cy2[k]  = v2f{c, c};
            sy2[k]  = v2f{s, s};
            nsy2[k] = v2f{-s, -s};
            th0n[k] = th_l[2 * k + 2];                   // theta0[k+1]
        }
    }
    __syncthreads();

    // ---- phase 2: coalesced stage of paw/pab ----
    {
        const float* gpw = paw + (size_t)blockIdx.x * TPB * REPS;
        const float* gpb = pab + (size_t)blockIdx.x * TPB * REPS;
#pragma unroll
        for (int p = 0; p < 8; ++p) {
            const int idx = p * TPB + t;
            const int row = idx / 8, col = idx % 8;
            lds[row * PW_PITCH + col] = gpw[idx];
            lds[TPB * PW_PITCH + row * PW_PITCH + col] = gpb[idx];
        }
    }
    __syncthreads();
#pragma unroll
    for (int k = 0; k < REPS; ++k) {
        wr_[k] = lds[t * PW_PITCH + k] * INV2PI;
        br_[k] = (lds[TPB * PW_PITCH + t * PW_PITCH + k] + th0n[k]) * INV2PI;
    }
    const float pw = postw[d];
    const float pb = postb[d];

    // ---- uniform poly constants: sin(2*pi*r)/cos(2*pi*r), |r|<=0.5 (Taylor) ----
    const v2f S13v = v2f{ 3.8199526f,  3.8199526f};   // vgpr (first Horner term)
    const v2f C12v = v2f{ 7.9035360f,  7.9035360f};
    const v2f S11 = v2f{-15.0946426f, -15.0946426f};  // the rest bind as sgpr pairs
    const v2f S9  = v2f{ 42.0586939f,  42.0586939f};
    const v2f S7  = v2f{-76.7058598f, -76.7058598f};
    const v2f S5  = v2f{ 81.6052493f,  81.6052493f};
    const v2f S3  = v2f{-41.3417022f, -41.3417022f};
    const v2f S1  = v2f{ 6.28318531f,  6.28318531f};
    const v2f C10 = v2f{-26.4262566f, -26.4262566f};
    const v2f C8  = v2f{ 60.2446439f,  60.2446439f};
    const v2f C6  = v2f{-85.4568172f, -85.4568172f};
    const v2f C4  = v2f{ 64.9393940f,  64.9393940f};
    const v2f C2  = v2f{-19.7392088f, -19.7392088f};
    const v2f ONE2 = v2f{1.0f, 1.0f};
    const v2f NEG1 = v2f{-1.0f, -1.0f};

    // nse = sin(2*pi*(m-f)) = -sin(2*pi*f);  ce = cos(2*pi*f). No sign logic.
    auto sc_rev = [&](v2f f, v2f& nse, v2f& ce) {
        v2f m2 = v2f{rintf(f.x), rintf(f.y)};
        v2f nr = pk_fma_bs(f, NEG1, m2);        // m - f, in [-0.5, 0.5]
        v2f r2 = pk_mul(nr, nr);
        v2f p  = pk_fma_cs(r2, S13v, S11);
        p = pk_fma_cs(p, r2, S9);
        p = pk_fma_cs(p, r2, S7);
        p = pk_fma_cs(p, r2, S5);
        p = pk_fma_cs(p, r2, S3);
        p = pk_fma_cs(p, r2, S1);
        nse = pk_mul(p, nr);
        v2f q  = pk_fma_cs(r2, C12v, C10);
        q = pk_fma_cs(q, r2, C8);
        q = pk_fma_cs(q, r2, C6);
        q = pk_fma_cs(q, r2, C4);
        q = pk_fma_cs(q, r2, C2);
        ce = pk_fma_cs(q, r2, ONE2);
    };

    // One float2 = two batch rows through the 8-rep circuit; returns final Z.
    auto run_chain = [&](v2f xv, v2f& zf) {
        v2f X, Y, Z, nse, ce, se;
        // r = 0: state (Xi,Yi,Zi), encode-only (RY folded into init)
        v2f f = v2f{fmaf(wr_[0], xv.x, br_[0]), fmaf(wr_[0], xv.y, br_[0])};
        sc_rev(f, nse, ce);
        X = pk_fma(Xi2, ce, pk_mul(Yi2, nse));          // Xi*ce - Yi*se
        se = pk_mul_bs(nse, NEG1);
        Y = pk_fma(Xi2, se, pk_mul(Yi2, ce));           // Xi*se + Yi*ce
        Z = Zi2;
#pragma unroll
        for (int r = 1; r < REPS; ++r) {
            const int k = r - 1;
            v2f Xb = pk_fma(Z, sy2[k], pk_mul(X, cy2[k]));    // X*cy + Z*sy
            v2f Zb = pk_fma(X, nsy2[k], pk_mul(Z, cy2[k]));   // Z*cy - X*sy
            f = v2f{fmaf(wr_[r], xv.x, br_[r]), fmaf(wr_[r], xv.y, br_[r])};
            sc_rev(f, nse, ce);
            v2f Xn = pk_fma(Xb, ce, pk_mul(Y, nse));          // Xb*ce - Y*se
            if (r < REPS - 1) {                                // Y dead after last rep
                se = pk_mul_bs(nse, NEG1);
                Y = pk_fma(Xb, se, pk_mul(Y, ce));             // Xb*se + Y*ce
            }
            X = Xn; Z = Zb;
        }
        zf = pk_fma(X, nsy2[REPS - 1], pk_mul(Z, cy2[REPS - 1]));  // final RY, Z only
    };

    // ---- main loop: 8 chunks x 4 rows, next-chunk x prefetched ----
    const int bbase = blockIdx.y * BPB;
    const float* xp = x + (size_t)bbase * DIM + d;
    float* op = out + (size_t)bbase * DIM + d;

    auto loadx = [&](int c, v2f& u, v2f& v) {
        const float* p = xp + (size_t)(c * 4) * DIM;
        u.x = p[0]; u.y = p[DIM];
        v.x = p[2 * (size_t)DIM]; v.y = p[3 * (size_t)DIM];
    };
    auto do_chunk = [&](v2f u, v2f v, int c) {
        v2f z0, z1;
        run_chain(u, z0);
        run_chain(v, z1);
        float* o = op + (size_t)(c * 4) * DIM;
        o[0]              = fmaf(z0.x, pw, pb);
        o[DIM]            = fmaf(z0.y, pw, pb);
        o[2 * (size_t)DIM] = fmaf(z1.x, pw, pb);
        o[3 * (size_t)DIM] = fmaf(z1.y, pw, pb);
    };

    v2f u, v, un, vn;
    loadx(0, u, v);
#pragma unroll 1
    for (int c = 0; c < NCH - 1; ++c) {
        loadx(c + 1, un, vn);     // hide HBM latency under ~900cy of compute
        do_chunk(u, v, c);
        u = un; v = vn;
    }
    do_chunk(u, v, NCH - 1);
}

extern "C" void kernel_launch(void* const* d_in, const int* in_sizes, int n_in,
                              void* d_out, int out_size, void* d_ws, size_t ws_size,
                              hipStream_t stream) {
    const float* x     = (const float*)d_in[0];
    const float* theta = (const float*)d_in[1];
    const float* paw   = (const float*)d_in[2];
    const float* pab   = (const float*)d_in[3];
    const float* postw = (const float*)d_in[4];
    const float* postb = (const float*)d_in[5];
    float* out = (float*)d_out;

    daruan_kernel<<<dim3(GRIDX, GRIDY), dim3(TPB), 0, stream>>>(
        x, theta, paw, pab, postw, postb, out);
}

// Round 6
// 35.636 us; speedup vs baseline: 1.1402x; 1.1402x over previous
//
#include <hip/hip_runtime.h>
#include <math.h>

constexpr int BATCH = 4096;
constexpr int DIM   = 2048;
constexpr int REPS  = 8;
constexpr float INV2PI = 0.15915494309189535f;  // 1/(2*pi)

constexpr int TPB   = 256;
constexpr int GRIDX = DIM / TPB;       // 8
constexpr int GRIDY = 256;             // 2048 blocks
constexpr int BPB   = BATCH / GRIDY;   // 16 rows per block
constexpr int ILP   = 4;
constexpr int NCH   = BPB / ILP;       // 4 chunks

// sin/cos of 2*pi*f (f in revolutions), full-period near-minimax.
// Chebyshev-truncated (Bessel J_n(pi) expansion), |err| ~<= 1e-4 on |r|<=0.5.
// 12 scalar VALU ops = 24 cy/wave vs 2 hw trans = 32 cy/wave.
__device__ __forceinline__ void sincos_rev(float f, float& s, float& c) {
    const float m = __builtin_rintf(f);   // v_rndne_f32
    const float r = f - m;                // |r| <= 0.5
    const float u = r * r;
    float p = fmaf(32.7680000f, u, -74.4701952f);   // sin: deg-9 odd
    p = fmaf(p, u, 81.3660160f);
    p = fmaf(p, u, -41.3311104f);
    p = fmaf(p, u, 6.2830536f);
    s = p * r;
    float q = fmaf(45.6130560f, u, -82.3881728f);   // cos: deg-8 even
    q = fmaf(q, u, 64.6713088f);
    q = fmaf(q, u, -19.7309120f);
    c = fmaf(q, u, 0.9999527f);
}

__global__ __launch_bounds__(TPB, 4)
void daruan_kernel(const float* __restrict__ x,       // (BATCH, DIM)
                   const float* __restrict__ theta,   // (DIM, 9, 2)
                   const float* __restrict__ paw,     // (DIM, 8)
                   const float* __restrict__ pab,     // (DIM, 8)
                   const float* __restrict__ postw,   // (DIM)
                   const float* __restrict__ postb,   // (DIM)
                   float* __restrict__ out)           // (BATCH, DIM)
{
    const int d = blockIdx.x * TPB + threadIdx.x;

    // ---- per-d preamble (amortized over 16 elements) ----
    // Trainable-RZ folding (verified R1-R4): RZ(t0[0])+RY(t1[0]) -> initial
    // Bloch state; RZ(t0[r+1]) (incl. final) absorbed into rep r's bias.
    const float* th = theta + (size_t)d * (REPS + 1) * 2;
    const float t00 = th[0] * INV2PI;
    const float X0  = __builtin_amdgcn_cosf(t00);
    const float Y0  = __builtin_amdgcn_sinf(t00);
    const float t10 = th[1] * INV2PI;
    const float Xi  = X0 * __builtin_amdgcn_cosf(t10);
    const float Yi  = Y0;
    const float Zi  = -X0 * __builtin_amdgcn_sinf(t10);

    float cy[REPS], sy[REPS], wr[REPS], br[REPS];
#pragma unroll
    for (int k = 0; k < REPS; ++k) {
        const float t1 = th[2 * k + 3] * INV2PI;        // theta1[k+1]
        cy[k] = __builtin_amdgcn_cosf(t1);
        sy[k] = __builtin_amdgcn_sinf(t1);
        wr[k] = paw[(size_t)d * REPS + k] * INV2PI;
        br[k] = (pab[(size_t)d * REPS + k] + th[2 * (k + 1)]) * INV2PI;
    }
    const float pw = postw[d];
    const float pb = postb[d];

    const int bbase = blockIdx.y * BPB;
    const float* xp = x + (size_t)bbase * DIM + d;
    float* op = out + (size_t)bbase * DIM + d;

    auto do_chunk = [&](const float (&xv)[ILP], int cc) {
        float X[ILP], Y[ILP], Z[ILP];
        // r = 0: state (Xi,Yi,Zi); only the encoded RZ (RY folded into init)
#pragma unroll
        for (int i = 0; i < ILP; ++i) {
            float se, ce;
            sincos_rev(fmaf(wr[0], xv[i], br[0]), se, ce);
            X[i] = fmaf(Xi, ce, -Yi * se);
            Y[i] = fmaf(Xi, se, Yi * ce);
            Z[i] = Zi;
        }
#pragma unroll
        for (int r = 1; r < REPS; ++r) {
#pragma unroll
            for (int i = 0; i < ILP; ++i) {
                const float Xb = fmaf(X[i], cy[r - 1], Z[i] * sy[r - 1]);
                const float Zb = fmaf(Z[i], cy[r - 1], -X[i] * sy[r - 1]);
                float se, ce;
                sincos_rev(fmaf(wr[r], xv[i], br[r]), se, ce);
                X[i] = fmaf(Xb, ce, -Y[i] * se);
                if (r < REPS - 1)                     // Y dead after last rep
                    Y[i] = fmaf(Xb, se, Y[i] * ce);
                Z[i] = Zb;
            }
        }
#pragma unroll
        for (int i = 0; i < ILP; ++i) {
            const float Zf = fmaf(Z[i], cy[REPS - 1], -X[i] * sy[REPS - 1]);
            op[(size_t)(cc * ILP + i) * DIM] = fmaf(Zf, pw, pb);
        }
    };

    float xv[ILP];
#pragma unroll
    for (int i = 0; i < ILP; ++i) xv[i] = xp[(size_t)i * DIM];

#pragma unroll 1
    for (int cc = 0; cc < NCH - 1; ++cc) {
        float xn[ILP];
#pragma unroll
        for (int i = 0; i < ILP; ++i)     // prefetch next chunk's x
            xn[i] = xp[(size_t)((cc + 1) * ILP + i) * DIM];
        do_chunk(xv, cc);
#pragma unroll
        for (int i = 0; i < ILP; ++i) xv[i] = xn[i];
    }
    do_chunk(xv, NCH - 1);
}

extern "C" void kernel_launch(void* const* d_in, const int* in_sizes, int n_in,
                              void* d_out, int out_size, void* d_ws, size_t ws_size,
                              hipStream_t stream) {
    const float* x     = (const float*)d_in[0];
    const float* theta = (const float*)d_in[1];
    const float* paw   = (const float*)d_in[2];
    const float* pab   = (const float*)d_in[3];
    const float* postw = (const float*)d_in[4];
    const float* postb = (const float*)d_in[5];
    float* out = (float*)d_out;

    daruan_kernel<<<dim3(GRIDX, GRIDY), dim3(TPB), 0, stream>>>(
        x, theta, paw, pab, postw, postb, out);
}